// Round 2
// baseline (375.374 us; speedup 1.0000x reference)
//
#include <hip/hip_runtime.h>
#include <math.h>

// CTC batch cost: B=256, T=256, C=1024, L=32 -> S=65 extended states.
// Key facts exploited:
//  * all even extended states are the blank class -> only 33 distinct
//    log-probs per (b,t): 32 labels + blank.
//  * one block (16 waves) per batch element: 16-way parallel gather into
//    LDS (each wave owns 16 timesteps, 16 outstanding scattered loads per
//    lane), then wave 0 runs the serial alpha recursion from LDS.

#define Bt 256
#define Tt 256
#define Ct 1024
#define Lt 32
#define NEGV (-1e30f)
#define EPSV (1e-7f)
#define WAVES 16
#define TPW (Tt / WAVES)    // 16 timesteps per wave
#define STRIDE 33           // labels 0..31 at [0..31], blank at [32]

__device__ __forceinline__ float lae2(float a, float b) {
    float m = fmaxf(a, b);
    return m + __logf(__expf(a - m) + __expf(b - m));
}
__device__ __forceinline__ float lae3(float a, float b, float c) {
    float m = fmaxf(fmaxf(a, b), c);
    return m + __logf(__expf(a - m) + __expf(b - m) + __expf(c - m));
}

__global__ __launch_bounds__(1024) void ctc_kernel(const int* __restrict__ y_true,
                                                   const float* __restrict__ y_pred,
                                                   float* __restrict__ out) {
    __shared__ float s_lp[Tt * STRIDE];   // 33792 B
    __shared__ float s_alpha[66];

    const int b = blockIdx.x;
    const int tid = threadIdx.x;
    const int w = tid >> 6;
    const int lane = tid & 63;
    const int blank = Ct - 1;
    const float* yp = y_pred + (size_t)b * Tt * Ct;
    const int* lab = y_true + b * Lt;

    // class gathered by this lane: labels for lanes 0..31, blank for lane 32
    int cls = blank;
    if (lane < 32) cls = lab[lane];

    // ---- phase 1: gather log-probs into LDS ----
    if (lane < 33) {
        const int t0 = w * TPW;
        float v[TPW];
        #pragma unroll
        for (int k = 0; k < TPW; ++k)
            v[k] = yp[(size_t)(t0 + k) * Ct + cls];
        #pragma unroll
        for (int k = 0; k < TPW; ++k)
            s_lp[(t0 + k) * STRIDE + lane] = __logf(v[k] + EPSV);
    }
    __syncthreads();

    // ---- phase 2: wave 0 runs the alpha recursion ----
    if (w == 0) {
        // skip-transition allowed into odd state 2*lane+1?
        bool allow = true;
        if (lane >= 1 && lane < 32) {
            int lprev = lab[lane - 1];
            allow = (cls != blank) && (cls != lprev);
        }

        // label length via ballot over nonzero labels
        unsigned long long nz = __ballot(lane < 32 && cls != 0);
        int ll = (int)__popcll(nz);

        float a_even, a_odd;
        {
            float le = s_lp[32];                                 // t=0 blank
            float lo = (lane < 32) ? s_lp[lane] : NEGV;          // t=0 labels
            a_even = (lane == 0) ? le : NEGV;
            a_odd  = (lane == 0) ? lo : NEGV;
        }

        #pragma unroll 4
        for (int t = 1; t < Tt; ++t) {
            float le = s_lp[t * STRIDE + 32];                    // broadcast
            float lo = (lane < 32) ? s_lp[t * STRIDE + lane] : NEGV;
            float po = __shfl_up(a_odd, 1);                      // old a[2i-1]
            if (lane == 0) po = NEGV;
            // even state 2i (blank): a1=a[2i], a2=a[2i-1]; no skip
            float ne = le + lae2(a_even, po);
            // odd state 2i+1: a1=a[2i+1], a2=a[2i] (old), a3=a[2i-1] if allowed
            float no = lo + lae3(a_odd, a_even, allow ? po : NEGV);
            a_even = ne;
            a_odd  = no;
        }

        if (lane < 33) {
            s_alpha[2 * lane] = a_even;
            if (lane < 32) s_alpha[2 * lane + 1] = a_odd;
        }
        __builtin_amdgcn_s_waitcnt(0);  // lgkmcnt(0) within-wave LDS ordering
        if (lane == 0) {
            int i1 = 2 * ll;
            int i2 = 2 * ll - 1;
            float v1 = s_alpha[i1];
            float v2 = (i2 >= 0) ? s_alpha[i2] : NEGV;
            out[b] = -lae2(v1, v2);
        }
    }
}

extern "C" void kernel_launch(void* const* d_in, const int* in_sizes, int n_in,
                              void* d_out, int out_size, void* d_ws, size_t ws_size,
                              hipStream_t stream) {
    const int* y_true = (const int*)d_in[0];
    const float* y_pred = (const float*)d_in[1];
    float* out = (float*)d_out;
    (void)in_sizes; (void)n_in; (void)out_size; (void)d_ws; (void)ws_size;
    ctc_kernel<<<Bt, 1024, 0, stream>>>(y_true, y_pred, out);
}